// Round 13
// baseline (198.937 us; speedup 1.0000x reference)
//
#include <hip/hip_runtime.h>

// ---------------------------------------------------------------------------
// FlashAttention_45844480917693 — cosine-sim attention, MI355X (gfx950)
// R13: attn K taken out of LDS — QK A-fragments live in registers (kreg[4][4],
// reloaded per-jt from L2-resident Kb right after consumption; barrier vmcnt
// drain guarantees next-tile availability). LDS halves to 32 KB (V only).
// Rest = R12: fused x-convert QKV GEMM, merged transposes, R8 attn schedule,
// XCD-local heads, register P via permlane32_swap.
// ---------------------------------------------------------------------------

typedef _Float16 f16;
typedef _Float16 f16x4 __attribute__((ext_vector_type(4)));
typedef _Float16 f16x8 __attribute__((ext_vector_type(8)));
typedef float f32x4 __attribute__((ext_vector_type(4)));
typedef float f32x16 __attribute__((ext_vector_type(16)));
typedef int i32x4 __attribute__((ext_vector_type(4)));

#define MFMA_F16(a, b, c) __builtin_amdgcn_mfma_f32_16x16x32_f16((a), (b), (c), 0, 0, 0)
#define MFMA32(a, b, c) __builtin_amdgcn_mfma_f32_32x32x16_f16((a), (b), (c), 0, 0, 0)

// 16 * log2(e)
#define QSCALE 23.083120654223414f
// exp2 bias: -QSCALE + 14 (P pre-scaled by 2^14, cancels in rowsum division)
#define EXPBIAS -9.083120654223414f

__device__ __forceinline__ void gl_lds16(const void* g, void* l) {
  // async global->LDS, 16B per lane; LDS dest = wave-uniform base + lane*16
  __builtin_amdgcn_global_load_lds(
      (const __attribute__((address_space(1))) void*)g,
      (__attribute__((address_space(3))) void*)l, 16, 0, 0);
}

// ---------------------------------------------------------------------------
// All weight transposes in one launch. z selects {Wq, Wkv-lo, Wkv-hi, Wo}.
__global__ void transpose_all_kernel(const float* __restrict__ Wq,
                                     const float* __restrict__ Wkv,
                                     const float* __restrict__ Wo,
                                     f16* __restrict__ Wqkv_t, f16* __restrict__ Wo_t) {
  __shared__ float t[64][65];
  const int z = blockIdx.z;
  const float* W; int ldw, col0, K, nc; f16* out;
  if (z == 0)      { W = Wq;  ldw = 512;  col0 = 0;   K = 1024; nc = 8;  out = Wqkv_t; }
  else if (z == 1) { W = Wkv; ldw = 1024; col0 = 0;   K = 1024; nc = 8;  out = Wqkv_t + 512 * 1024; }
  else if (z == 2) { W = Wkv; ldw = 1024; col0 = 512; K = 1024; nc = 8;  out = Wqkv_t + 1024 * 1024; }
  else             { W = Wo;  ldw = 1024; col0 = 0;   K = 512;  nc = 16; out = Wo_t; }
  if ((int)blockIdx.x >= nc || (int)blockIdx.y >= (K >> 6)) return;
  int tx = threadIdx.x, ty = threadIdx.y;
  int c0 = blockIdx.x * 64, k0 = blockIdx.y * 64;
#pragma unroll
  for (int i = 0; i < 8; i++)
    t[ty + i * 8][tx] = W[(long)(k0 + ty + i * 8) * ldw + col0 + c0 + tx];
  __syncthreads();
#pragma unroll
  for (int i = 0; i < 8; i++)
    out[(long)(c0 + ty + i * 8) * K + k0 + tx] = (f16)t[tx][ty + i * 8];
}

// Vb [bh][n][64] -> Vt [bh][64][n], 64x64 f16 tiles, swizzled LDS
__global__ void transpose_v_kernel(const f16* __restrict__ Vb, f16* __restrict__ Vt, int n) {
  __shared__ f16 t[64 * 64];
  const int tid = threadIdx.x;
  const int bh = blockIdx.y;
  const int n0 = blockIdx.x * 64;
  const f16* src = Vb + ((long)bh * n + n0) * 64;
  const int j = tid >> 3, c = tid & 7;
  f16x8 v0 = *(const f16x8*)(src + j * 64 + c * 8);
  f16x8 v1 = *(const f16x8*)(src + (j + 32) * 64 + c * 8);
  *(f16x8*)(&t[j * 64 + ((c ^ (j & 7)) << 3)]) = v0;
  *(f16x8*)(&t[(j + 32) * 64 + ((c ^ (j & 7)) << 3)]) = v1;  // (j+32)&7 == j&7
  __syncthreads();
  const int d = tid >> 3, cj = tid & 7;
  f16x8 o0, o1;
#pragma unroll
  for (int e = 0; e < 8; e++) {
    int jj = cj * 8 + e;
    o0[e] = t[jj * 64 + (((d >> 3) ^ (jj & 7)) << 3) + (d & 7)];
    o1[e] = t[jj * 64 + ((((d + 32) >> 3) ^ (jj & 7)) << 3) + ((d + 32) & 7)];
  }
  *(f16x8*)(Vt + ((long)bh * 64 + d) * n + n0 + cj * 8) = o0;
  *(f16x8*)(Vt + ((long)bh * 64 + d + 32) * n + n0 + cj * 8) = o1;
}

// ---------------------------------------------------------------------------
// GEMM: C[M][N] = A[M][K] * Bt[N][K]^T, 128x128 tile, BK=32, 4 waves (2x2).
// MODE 0: A fp16 via gl_lds, fp32 C out.
// MODE 1: A = x fp32, reg-staged + converted to fp16 in-register; fused QKV
//         epilogue (l2norm for Q/K; Q pre-scaled by 16*log2e).
template <int MODE>
__global__ __launch_bounds__(256, 3)
void gemm_kernel(const f16* __restrict__ A, const f16* __restrict__ Bt,
                 float* __restrict__ C,
                 f16* __restrict__ Qb, f16* __restrict__ Kb, f16* __restrict__ Vb,
                 const float* __restrict__ Axf,
                 int M, int N, int K) {
  __shared__ f16 As[128 * 32];
  __shared__ f16 Bs[128 * 32];
  const int tid = threadIdx.x;
  const int lane = tid & 63;
  const int wid = tid >> 6;
  const int wr = wid >> 1, wc = wid & 1;
  const int lr = lane & 15, lk = lane >> 4;
  const int lin = blockIdx.x;
  const int bx = ((lin & 7) << 3) | ((lin >> 3) & 7);  // XCD (lin%8) owns 8 x-panels
  const int by = lin >> 6;
  const long m0 = (long)bx * 128;
  const int n0 = by * 128;

  f32x4 acc[4][4] = {};

  const int c0 = tid, c1 = tid + 256;
  const int ar0 = c0 >> 2, ah0 = (c0 & 3) ^ ((ar0 >> 1) & 3);
  const int ar1 = c1 >> 2, ah1 = (c1 & 3) ^ ((ar1 >> 1) & 3);
  const f16* pa0 = A + (m0 + ar0) * K + ah0 * 8;
  const f16* pa1 = A + (m0 + ar1) * K + ah1 * 8;
  const float* pa0f = Axf + (m0 + ar0) * K + ah0 * 8;
  const float* pa1f = Axf + (m0 + ar1) * K + ah1 * 8;
  const f16* pb0 = Bt + (long)(n0 + ar0) * K + ah0 * 8;
  const f16* pb1 = Bt + (long)(n0 + ar1) * K + ah1 * 8;

  // MODE 1: A-tile registers (8 fp32 per chunk, 2 chunks)
  float4 a00, a01, a10, a11;
  if (MODE == 1) {
    a00 = *(const float4*)(pa0f);
    a01 = *(const float4*)(pa0f + 4);
    a10 = *(const float4*)(pa1f);
    a11 = *(const float4*)(pa1f + 4);
  }

  for (int k0 = 0; k0 < K; k0 += 32) {
    __syncthreads();          // previous tile fully consumed
    if (MODE == 1) {
      f16x8 w0, w1;
#pragma unroll
      for (int e = 0; e < 4; e++) {
        w0[e] = (f16)(&a00.x)[e];
        w0[4 + e] = (f16)(&a01.x)[e];
        w1[e] = (f16)(&a10.x)[e];
        w1[4 + e] = (f16)(&a11.x)[e];
      }
      *(f16x8*)(As + c0 * 8) = w0;
      *(f16x8*)(As + c1 * 8) = w1;
    } else {
      gl_lds16(pa0 + k0, As + c0 * 8);
      gl_lds16(pa1 + k0, As + c1 * 8);
    }
    gl_lds16(pb0 + k0, Bs + c0 * 8);
    gl_lds16(pb1 + k0, Bs + c1 * 8);
    __syncthreads();          // staging complete (drains vmcnt + lgkmcnt)

    // issue next A-tile loads — latency hidden under the MFMA phase below
    if (MODE == 1 && k0 + 32 < K) {
      a00 = *(const float4*)(pa0f + k0 + 32);
      a01 = *(const float4*)(pa0f + k0 + 36);
      a10 = *(const float4*)(pa1f + k0 + 32);
      a11 = *(const float4*)(pa1f + k0 + 36);
    }

    f16x8 af[4], bf[4];
#pragma unroll
    for (int mi = 0; mi < 4; mi++) {
      int row = wr * 64 + mi * 16 + lr;
      int ch = lk ^ ((row >> 1) & 3);
      af[mi] = *(const f16x8*)(As + row * 32 + ch * 8);
    }
#pragma unroll
    for (int ni = 0; ni < 4; ni++) {
      int row = wc * 64 + ni * 16 + lr;
      int ch = lk ^ ((row >> 1) & 3);
      bf[ni] = *(const f16x8*)(Bs + row * 32 + ch * 8);
    }
    __builtin_amdgcn_s_setprio(1);
#pragma unroll
    for (int mi = 0; mi < 4; mi++)
#pragma unroll
      for (int ni = 0; ni < 4; ni++)
        acc[mi][ni] = MFMA_F16(af[mi], bf[ni], acc[mi][ni]);
    __builtin_amdgcn_s_setprio(0);
  }

  if (MODE == 0) {
#pragma unroll
    for (int mi = 0; mi < 4; mi++) {
      long mrow = m0 + wr * 64 + mi * 16 + lk * 4;
#pragma unroll
      for (int r = 0; r < 4; r++)
#pragma unroll
        for (int ni = 0; ni < 4; ni++)
          C[(mrow + r) * N + n0 + wc * 64 + ni * 16 + lr] = acc[mi][ni][r];
    }
  } else {
    const int region = by >> 2;                      // 0=Q, 1=K, 2=V
    const int head = (by & 3) * 2 + wc;
    f16* buf = (region == 0) ? Qb : ((region == 1) ? Kb : Vb);
    const float nscale = (region == 0) ? QSCALE : 1.f;  // Q pre-scaled
#pragma unroll
    for (int mi = 0; mi < 4; mi++) {
      float scl[4];
      if (region < 2) {
#pragma unroll
        for (int r = 0; r < 4; r++) {
          float s2 = 0.f;
#pragma unroll
          for (int ni = 0; ni < 4; ni++) s2 += acc[mi][ni][r] * acc[mi][ni][r];
          s2 += __shfl_xor(s2, 1);
          s2 += __shfl_xor(s2, 2);
          s2 += __shfl_xor(s2, 4);
          s2 += __shfl_xor(s2, 8);
          scl[r] = nscale / fmaxf(sqrtf(s2), 1e-12f);
        }
      } else {
#pragma unroll
        for (int r = 0; r < 4; r++) scl[r] = 1.f;
      }
#pragma unroll
      for (int r = 0; r < 4; r++) {
        int m = (int)m0 + wr * 64 + mi * 16 + lk * 4 + r;
        int bb = m >> 12, nn = m & 4095;
        f16* dst = buf + (((long)(bb * 8 + head) * 4096 + nn) << 6);
#pragma unroll
        for (int ni = 0; ni < 4; ni++)
          dst[ni * 16 + lr] = (f16)(acc[mi][ni][r] * scl[r]);
      }
    }
  }
}

// ---------------------------------------------------------------------------
// Attention v10: 32x32x16 MFMA, 4 waves x 32 q, KVBLK=128. K fragments in
// REGISTERS (kreg[jt][kc], loaded from L2-resident Kb; per-jt reload for
// tile t+1 issued right after QK(jt) consumes them — barrier vmcnt drain
// guarantees arrival). V double-buffered in LDS (32 KB total). Softmax
// folded into MFMA C-init; register P via permlane32_swap; fdot2 rowsum.
__global__ __launch_bounds__(256, 2)
void attn_kernel(const f16* __restrict__ Qb, const f16* __restrict__ Kb,
                 const f16* __restrict__ Vt, f16* __restrict__ Ob, int n) {
  __shared__ f16 Vs[2][64 * 128];    // [d][j], 16B-chunk ^= (d&15)  16KB x2
  const int tid = threadIdx.x, lane = tid & 63, wid = tid >> 6;  // wid 0..3
  const int ql = lane & 31, hi = lane >> 5;
  const int lin = blockIdx.x;
  const int bh = (lin & 7) | ((lin >> 8) << 3);
  const int qx = (lin >> 3) & 31;
  const long nl = n;
  const f16* Qg = Qb + (long)bh * nl * 64;
  const f16* Kg = Kb + (long)bh * nl * 64;
  const f16* Vg = Vt + (long)bh * 64 * nl;
  const int q0w = qx * 128 + wid * 32;

  // Q fragments (B-operand): col q = ql, k d = kc*16 + hi*8 + e
  f16x8 qf[4];
#pragma unroll
  for (int kc = 0; kc < 4; kc++)
    qf[kc] = *(const f16x8*)(Qg + (long)(q0w + ql) * 64 + kc * 16 + hi * 8);

  // V staging source offsets; LDS dest lane-linear, source pre-swizzled.
  int vsrc[4];
#pragma unroll
  for (int p = 0; p < 4; p++) {
    const int ci = tid + p * 256;
    const int vd = ci >> 4, vc = ci & 15;
    vsrc[p] = vd * n + ((vc ^ (vd & 15)) << 3);
  }

  // K A-fragments in registers: lane reads Kg[(jt*32+ql)*64 + kc*16 + hi*8]
  const f16* Kw = Kg + (long)ql * 64 + hi * 8;    // per-lane K base
  f16x8 kreg[4][4];
#pragma unroll
  for (int jt = 0; jt < 4; jt++)
#pragma unroll
    for (int kc = 0; kc < 4; kc++)
      kreg[jt][kc] = *(const f16x8*)(Kw + (jt * 32) * 64 + kc * 16);

  f32x16 oacc[2][2] = {};   // [kl][dt] — 4 independent MFMA chains
  float rsum0 = 0.f, rsum1 = 0.f;
  f32x16 initv;
#pragma unroll
  for (int e = 0; e < 16; e++) initv[e] = EXPBIAS;
  const auto one2 = __builtin_amdgcn_cvt_pkrtz(1.f, 1.f);

  // prologue: stage V(0) into buf 0
#pragma unroll
  for (int p = 0; p < 4; p++)
    gl_lds16(Vg + vsrc[p], &Vs[0][(tid + p * 256) * 8]);
  __syncthreads();

  const int nt = n >> 7;
  for (int t = 0; t < nt; t++) {
    const int cur = t & 1;
    if (t + 1 < nt) {
      const long vadv = (long)(t + 1) << 7;     // +128 j
#pragma unroll
      for (int p = 0; p < 4; p++)
        gl_lds16(Vg + vadv + vsrc[p], &Vs[cur ^ 1][(tid + p * 256) * 8]);
    }
    // next-tile K base (wrapped on last tile to stay in-bounds; values unused)
    const long knext = ((long)((t + 1) & (nt - 1)) << 7) * 64;

#pragma unroll
    for (int jt = 0; jt < 4; jt++) {
      // QK(jt) from registers — no LDS dependency
      __builtin_amdgcn_s_setprio(1);
      f32x16 s = MFMA32(kreg[jt][0], qf[0], initv);
      s = MFMA32(kreg[jt][1], qf[1], s);
      s = MFMA32(kreg[jt][2], qf[2], s);
      s = MFMA32(kreg[jt][3], qf[3], s);
      __builtin_amdgcn_s_setprio(0);

      // kreg[jt] now dead — reload for tile t+1 (L2 hit; latency hidden
      // under remaining softmax/PV; barrier vmcnt drain guarantees arrival)
#pragma unroll
      for (int kc = 0; kc < 4; kc++)
        kreg[jt][kc] = *(const f16x8*)(Kw + knext + (jt * 32) * 64 + kc * 16);

      // softmax: exp2 -> pack -> fdot2 rowsum (2 chains)
      int w[8];
#pragma unroll
      for (int m = 0; m < 8; m++) {
        const float pa = __builtin_amdgcn_exp2f(s[2 * m]);
        const float pb = __builtin_amdgcn_exp2f(s[2 * m + 1]);
        const auto h = __builtin_amdgcn_cvt_pkrtz(pa, pb);
        if (m & 1)
          rsum1 = __builtin_amdgcn_fdot2(h, one2, rsum1, false);
        else
          rsum0 = __builtin_amdgcn_fdot2(h, one2, rsum0, false);
        w[m] = __builtin_bit_cast(int, h);
      }
#pragma unroll
      for (int kl = 0; kl < 2; kl++) {
        int a0 = w[4 * kl + 0], a1 = w[4 * kl + 1];
        int a2 = w[4 * kl + 2], a3 = w[4 * kl + 3];
        // v_permlane32_swap: dst.hi32lanes <-> src.lo32lanes
        asm volatile("v_permlane32_swap_b32 %0, %1" : "+v"(a0), "+v"(a2));
        asm volatile("v_permlane32_swap_b32 %0, %1" : "+v"(a1), "+v"(a3));
        i32x4 fi = {a0, a1, a2, a3};
        const f16x8 pfrag = __builtin_bit_cast(f16x8, fi);
        const int kb = jt * 2 + kl;
        __builtin_amdgcn_s_setprio(1);
#pragma unroll
        for (int dt = 0; dt < 2; dt++) {
          const int d = dt * 32 + ql;
          const f16x8 vf =
              *(const f16x8*)(&Vs[cur][d * 128 + ((((kb << 1) | hi) ^ (d & 15)) << 3)]);
          oacc[kl][dt] = MFMA32(pfrag, vf, oacc[kl][dt]);
        }
        __builtin_amdgcn_s_setprio(0);
      }
    }

    __syncthreads();  // drains prefetch vmcnt (V + kreg) + all waves done
  }

  // final rowsum (other hi-half holds complementary j's), divide, store
  float rsum = rsum0 + rsum1;
  rsum += __shfl_xor(rsum, 32);
  const int bb = bh >> 3, hh = bh & 7;
#pragma unroll
  for (int r = 0; r < 16; r++) {
    const int qloc = (r & 3) + 8 * (r >> 2) + 4 * hi;
    const float sm = __shfl(rsum, qloc);                // rowsum for q0w+qloc
    const float inv = 1.f / fmaxf(sm, 0.016384f);       // 1e-6 * 2^14
    f16* dst = Ob + (((long)(bb * 4096 + q0w + qloc)) << 9) + hh * 64;
    dst[ql] = (f16)((oacc[0][0][r] + oacc[1][0][r]) * inv);
    dst[32 + ql] = (f16)((oacc[0][1][r] + oacc[1][1][r]) * inv);
  }
}

// ---------------------------------------------------------------------------
extern "C" void kernel_launch(void* const* d_in, const int* in_sizes, int n_in,
                              void* d_out, int out_size, void* d_ws, size_t ws_size,
                              hipStream_t stream) {
  const float* x   = (const float*)d_in[0];   // [2,4096,1024]
  const float* Wq  = (const float*)d_in[1];   // [1024,512]
  const float* Wkv = (const float*)d_in[2];   // [1024,1024]
  const float* Wo  = (const float*)d_in[3];   // [512,1024]
  float* out = (float*)d_out;                 // [2,4096,1024] fp32

  char* ws = (char*)d_ws;
  f16* Vt     = (f16*)(ws);                   //  8.39 MB  [16][64][4096]
  f16* Wqkv_t = (f16*)(ws + 16777216);        //  3.15 MB  [1536][1024]
  f16* Wo_t   = (f16*)(ws + 19922944);        //  1.05 MB  [1024][512]
  f16* Qb     = (f16*)(ws + 20971520);        //  8.39 MB  [16][4096][64]
  f16* Kb     = (f16*)(ws + 29360128);        //  8.39 MB
  f16* Vb     = (f16*)(ws + 37748736);        //  8.39 MB
  f16* At     = (f16*)(ws + 46137344);        //  8.39 MB  [8192][512]

  // all weight transposes in one launch
  transpose_all_kernel<<<dim3(16, 16, 4), dim3(64, 8), 0, stream>>>(Wq, Wkv, Wo, Wqkv_t, Wo_t);

  // fused x-convert + QKV projection + l2norm (+Q prescale): [8192 x 1536 x 1024]
  gemm_kernel<1><<<768, 256, 0, stream>>>(nullptr, Wqkv_t, nullptr, Qb, Kb, Vb, x,
                                          8192, 1536, 1024);
  // V -> V^T
  transpose_v_kernel<<<dim3(64, 16), 256, 0, stream>>>(Vb, Vt, 4096);
  // attention (512 blocks, XCD-decoded inside)
  attn_kernel<<<512, 256, 0, stream>>>(Qb, Kb, Vt, At, 4096);
  // output projection: [8192 x 1024 x 512]
  gemm_kernel<0><<<512, 256, 0, stream>>>(At, Wo_t, out, nullptr, nullptr, nullptr, nullptr,
                                          8192, 1024, 512);
}

// Round 14
// 149.494 us; speedup vs baseline: 1.3307x; 1.3307x over previous
//
#include <hip/hip_runtime.h>

// ---------------------------------------------------------------------------
// FlashAttention_45844480917693 — cosine-sim attention, MI355X (gfx950)
// R14: revert attn to R12 (best: 89 µs) + fuse V-transpose into the QKV GEMM
// epilogue (V-region blocks bounce their tile through padded LDS and write
// Vt[bh][d][n] directly, coalesced) — transpose_v kernel and Vb buffer
// deleted. Rest = R12: fused x-convert QKV GEMM, merged weight transposes,
// XCD-local decode, register-P attn via permlane32_swap.
// ---------------------------------------------------------------------------

typedef _Float16 f16;
typedef _Float16 f16x4 __attribute__((ext_vector_type(4)));
typedef _Float16 f16x8 __attribute__((ext_vector_type(8)));
typedef float f32x4 __attribute__((ext_vector_type(4)));
typedef float f32x16 __attribute__((ext_vector_type(16)));
typedef int i32x4 __attribute__((ext_vector_type(4)));

#define MFMA_F16(a, b, c) __builtin_amdgcn_mfma_f32_16x16x32_f16((a), (b), (c), 0, 0, 0)
#define MFMA32(a, b, c) __builtin_amdgcn_mfma_f32_32x32x16_f16((a), (b), (c), 0, 0, 0)

// 16 * log2(e)
#define QSCALE 23.083120654223414f
// exp2 bias: -QSCALE + 14 (P pre-scaled by 2^14, cancels in rowsum division)
#define EXPBIAS -9.083120654223414f

__device__ __forceinline__ void gl_lds16(const void* g, void* l) {
  // async global->LDS, 16B per lane; LDS dest = wave-uniform base + lane*16
  __builtin_amdgcn_global_load_lds(
      (const __attribute__((address_space(1))) void*)g,
      (__attribute__((address_space(3))) void*)l, 16, 0, 0);
}

// ---------------------------------------------------------------------------
// All weight transposes in one launch. z selects {Wq, Wkv-lo, Wkv-hi, Wo}.
__global__ void transpose_all_kernel(const float* __restrict__ Wq,
                                     const float* __restrict__ Wkv,
                                     const float* __restrict__ Wo,
                                     f16* __restrict__ Wqkv_t, f16* __restrict__ Wo_t) {
  __shared__ float t[64][65];
  const int z = blockIdx.z;
  const float* W; int ldw, col0, K, nc; f16* out;
  if (z == 0)      { W = Wq;  ldw = 512;  col0 = 0;   K = 1024; nc = 8;  out = Wqkv_t; }
  else if (z == 1) { W = Wkv; ldw = 1024; col0 = 0;   K = 1024; nc = 8;  out = Wqkv_t + 512 * 1024; }
  else if (z == 2) { W = Wkv; ldw = 1024; col0 = 512; K = 1024; nc = 8;  out = Wqkv_t + 1024 * 1024; }
  else             { W = Wo;  ldw = 1024; col0 = 0;   K = 512;  nc = 16; out = Wo_t; }
  if ((int)blockIdx.x >= nc || (int)blockIdx.y >= (K >> 6)) return;
  int tx = threadIdx.x, ty = threadIdx.y;
  int c0 = blockIdx.x * 64, k0 = blockIdx.y * 64;
#pragma unroll
  for (int i = 0; i < 8; i++)
    t[ty + i * 8][tx] = W[(long)(k0 + ty + i * 8) * ldw + col0 + c0 + tx];
  __syncthreads();
#pragma unroll
  for (int i = 0; i < 8; i++)
    out[(long)(c0 + ty + i * 8) * K + k0 + tx] = (f16)t[tx][ty + i * 8];
}

// ---------------------------------------------------------------------------
// GEMM: C[M][N] = A[M][K] * Bt[N][K]^T, 128x128 tile, BK=32, 4 waves (2x2).
// MODE 0: A fp16 via gl_lds, fp32 C out.
// MODE 1: A = x fp32, reg-staged + converted to fp16 in-register; fused QKV
//         epilogue: Q/K l2norm (+Q prescale) direct store; V written
//         TRANSPOSED to Vt[bh][d][n] via padded-LDS bounce (coalesced).
template <int MODE>
__global__ __launch_bounds__(256, 3)
void gemm_kernel(const f16* __restrict__ A, const f16* __restrict__ Bt,
                 float* __restrict__ C,
                 f16* __restrict__ Qb, f16* __restrict__ Kb, f16* __restrict__ Vtb,
                 const float* __restrict__ Axf,
                 int M, int N, int K) {
  __shared__ f16 As[128 * 32];
  __shared__ f16 Bs[128 * 32];
  const int tid = threadIdx.x;
  const int lane = tid & 63;
  const int wid = tid >> 6;
  const int wr = wid >> 1, wc = wid & 1;
  const int lr = lane & 15, lk = lane >> 4;
  const int lin = blockIdx.x;
  const int bx = ((lin & 7) << 3) | ((lin >> 3) & 7);  // XCD (lin%8) owns 8 x-panels
  const int by = lin >> 6;
  const long m0 = (long)bx * 128;
  const int n0 = by * 128;

  f32x4 acc[4][4] = {};

  const int c0 = tid, c1 = tid + 256;
  const int ar0 = c0 >> 2, ah0 = (c0 & 3) ^ ((ar0 >> 1) & 3);
  const int ar1 = c1 >> 2, ah1 = (c1 & 3) ^ ((ar1 >> 1) & 3);
  const f16* pa0 = A + (m0 + ar0) * K + ah0 * 8;
  const f16* pa1 = A + (m0 + ar1) * K + ah1 * 8;
  const float* pa0f = Axf + (m0 + ar0) * K + ah0 * 8;
  const float* pa1f = Axf + (m0 + ar1) * K + ah1 * 8;
  const f16* pb0 = Bt + (long)(n0 + ar0) * K + ah0 * 8;
  const f16* pb1 = Bt + (long)(n0 + ar1) * K + ah1 * 8;

  // MODE 1: A-tile registers (8 fp32 per chunk, 2 chunks)
  float4 a00, a01, a10, a11;
  if (MODE == 1) {
    a00 = *(const float4*)(pa0f);
    a01 = *(const float4*)(pa0f + 4);
    a10 = *(const float4*)(pa1f);
    a11 = *(const float4*)(pa1f + 4);
  }

  for (int k0 = 0; k0 < K; k0 += 32) {
    __syncthreads();          // previous tile fully consumed
    if (MODE == 1) {
      f16x8 w0, w1;
#pragma unroll
      for (int e = 0; e < 4; e++) {
        w0[e] = (f16)(&a00.x)[e];
        w0[4 + e] = (f16)(&a01.x)[e];
        w1[e] = (f16)(&a10.x)[e];
        w1[4 + e] = (f16)(&a11.x)[e];
      }
      *(f16x8*)(As + c0 * 8) = w0;
      *(f16x8*)(As + c1 * 8) = w1;
    } else {
      gl_lds16(pa0 + k0, As + c0 * 8);
      gl_lds16(pa1 + k0, As + c1 * 8);
    }
    gl_lds16(pb0 + k0, Bs + c0 * 8);
    gl_lds16(pb1 + k0, Bs + c1 * 8);
    __syncthreads();          // staging complete (drains vmcnt + lgkmcnt)

    // issue next A-tile loads — latency hidden under the MFMA phase below
    if (MODE == 1 && k0 + 32 < K) {
      a00 = *(const float4*)(pa0f + k0 + 32);
      a01 = *(const float4*)(pa0f + k0 + 36);
      a10 = *(const float4*)(pa1f + k0 + 32);
      a11 = *(const float4*)(pa1f + k0 + 36);
    }

    f16x8 af[4], bf[4];
#pragma unroll
    for (int mi = 0; mi < 4; mi++) {
      int row = wr * 64 + mi * 16 + lr;
      int ch = lk ^ ((row >> 1) & 3);
      af[mi] = *(const f16x8*)(As + row * 32 + ch * 8);
    }
#pragma unroll
    for (int ni = 0; ni < 4; ni++) {
      int row = wc * 64 + ni * 16 + lr;
      int ch = lk ^ ((row >> 1) & 3);
      bf[ni] = *(const f16x8*)(Bs + row * 32 + ch * 8);
    }
    __builtin_amdgcn_s_setprio(1);
#pragma unroll
    for (int mi = 0; mi < 4; mi++)
#pragma unroll
      for (int ni = 0; ni < 4; ni++)
        acc[mi][ni] = MFMA_F16(af[mi], bf[ni], acc[mi][ni]);
    __builtin_amdgcn_s_setprio(0);
  }

  if constexpr (MODE == 0) {
#pragma unroll
    for (int mi = 0; mi < 4; mi++) {
      long mrow = m0 + wr * 64 + mi * 16 + lk * 4;
#pragma unroll
      for (int r = 0; r < 4; r++)
#pragma unroll
        for (int ni = 0; ni < 4; ni++)
          C[(mrow + r) * N + n0 + wc * 64 + ni * 16 + lr] = acc[mi][ni][r];
    }
  } else {
    const int region = by >> 2;                      // 0=Q, 1=K, 2=V
    if (region < 2) {
      const int head = (by & 3) * 2 + wc;
      f16* buf = (region == 0) ? Qb : Kb;
      const float nscale = (region == 0) ? QSCALE : 1.f;  // Q pre-scaled
#pragma unroll
      for (int mi = 0; mi < 4; mi++) {
        float scl[4];
#pragma unroll
        for (int r = 0; r < 4; r++) {
          float s2 = 0.f;
#pragma unroll
          for (int ni = 0; ni < 4; ni++) s2 += acc[mi][ni][r] * acc[mi][ni][r];
          s2 += __shfl_xor(s2, 1);
          s2 += __shfl_xor(s2, 2);
          s2 += __shfl_xor(s2, 4);
          s2 += __shfl_xor(s2, 8);
          scl[r] = nscale / fmaxf(sqrtf(s2), 1e-12f);
        }
#pragma unroll
        for (int r = 0; r < 4; r++) {
          int m = (int)m0 + wr * 64 + mi * 16 + lk * 4 + r;
          int bb = m >> 12, nn = m & 4095;
          f16* dst = buf + (((long)(bb * 8 + head) * 4096 + nn) << 6);
#pragma unroll
          for (int ni = 0; ni < 4; ni++)
            dst[ni * 16 + lr] = (f16)(acc[mi][ni][r] * scl[r]);
        }
      }
    } else {
      // V region: write transposed to Vt[bh][d][n] via padded LDS bounce.
      __shared__ f16 Ts[128 * 136];   // [row n_local][col], pad -> 272B rows
#pragma unroll
      for (int mi = 0; mi < 4; mi++)
#pragma unroll
        for (int r = 0; r < 4; r++) {
          const int row = wr * 64 + mi * 16 + lk * 4 + r;
#pragma unroll
          for (int ni = 0; ni < 4; ni++)
            Ts[row * 136 + wc * 64 + ni * 16 + lr] = (f16)acc[mi][ni][r];
        }
      __syncthreads();
      const int bb = (int)(m0 >> 12), nloc0 = (int)(m0 & 4095);
#pragma unroll
      for (int i = 0; i < 8; i++) {
        const int chunk = tid + i * 256;         // 2048 chunks: [r128][cc]
        const int r128 = chunk >> 4, cc = chunk & 15;
        const int head2 = (by & 3) * 2 + (r128 >> 6), d = r128 & 63;
        f16x8 v;
#pragma unroll
        for (int e = 0; e < 8; e++) v[e] = Ts[(cc * 8 + e) * 136 + r128];
        *(f16x8*)(Vtb + (((long)((bb * 8 + head2) * 64 + d)) << 12) + nloc0 + cc * 8) = v;
      }
    }
  }
}

// ---------------------------------------------------------------------------
// Attention (R8/R12 structure, best measured 89 µs): 32x32x16 MFMA, 4 waves
// x 32 q, KVBLK=128, K+V double-buffered (64 KB), one barrier/tile. Software-
// pipelined sub-tiles: QK(jt+1) issued before softmax(jt). P register-
// resident via permlane32_swap; rowsum via 2 independent fdot2 chains.
__global__ __launch_bounds__(256, 2)
void attn_kernel(const f16* __restrict__ Qb, const f16* __restrict__ Kb,
                 const f16* __restrict__ Vt, f16* __restrict__ Ob, int n) {
  __shared__ f16 Ks[2][128 * 64];    // [j][d], 16B-chunk ^= (j&7)   16KB x2
  __shared__ f16 Vs[2][64 * 128];    // [d][j], 16B-chunk ^= (d&15)  16KB x2
  const int tid = threadIdx.x, lane = tid & 63, wid = tid >> 6;  // wid 0..3
  const int ql = lane & 31, hi = lane >> 5;
  const int lin = blockIdx.x;
  const int bh = (lin & 7) | ((lin >> 8) << 3);
  const int qx = (lin >> 3) & 31;
  const long nl = n;
  const f16* Qg = Qb + (long)bh * nl * 64;
  const f16* Kg = Kb + (long)bh * nl * 64;
  const f16* Vg = Vt + (long)bh * 64 * nl;
  const int q0w = qx * 128 + wid * 32;

  // Q fragments (B-operand): col q = ql, k d = kc*16 + hi*8 + e
  f16x8 qf[4];
#pragma unroll
  for (int kc = 0; kc < 4; kc++)
    qf[kc] = *(const f16x8*)(Qg + (long)(q0w + ql) * 64 + kc * 16 + hi * 8);

  // staging source offsets (4 K-chunks + 4 V-chunks per thread per tile);
  // LDS dest stays lane-linear, source pre-swizzled.
  int ksrc[4], vsrc[4];
#pragma unroll
  for (int p = 0; p < 4; p++) {
    const int ci = tid + p * 256;
    const int kj = ci >> 3, kc_ = ci & 7;
    ksrc[p] = kj * 64 + ((kc_ ^ (kj & 7)) << 3);
    const int vd = ci >> 4, vc = ci & 15;
    vsrc[p] = vd * n + ((vc ^ (vd & 15)) << 3);
  }

  f32x16 oacc[2][2] = {};   // [kl][dt] — 4 independent MFMA chains
  float rsum0 = 0.f, rsum1 = 0.f;
  f32x16 initv;
#pragma unroll
  for (int e = 0; e < 16; e++) initv[e] = EXPBIAS;
  const auto one2 = __builtin_amdgcn_cvt_pkrtz(1.f, 1.f);

  // prologue: stage tile 0 into buf 0
#pragma unroll
  for (int p = 0; p < 4; p++) {
    gl_lds16(Kg + ksrc[p], &Ks[0][(tid + p * 256) * 8]);
    gl_lds16(Vg + vsrc[p], &Vs[0][(tid + p * 256) * 8]);
  }
  __syncthreads();

  const int nt = n >> 7;
  for (int t = 0; t < nt; t++) {
    const int cur = t & 1;
    if (t + 1 < nt) {
      const long kadv = (long)(t + 1) * 8192;   // 128 rows * 64 d
      const long vadv = (long)(t + 1) * 128;    // +128 j
#pragma unroll
      for (int p = 0; p < 4; p++) {
        gl_lds16(Kg + kadv + ksrc[p], &Ks[cur ^ 1][(tid + p * 256) * 8]);
        gl_lds16(Vg + vadv + vsrc[p], &Vs[cur ^ 1][(tid + p * 256) * 8]);
      }
    }

    // ---- software pipeline over 32-j sub-tiles ----
    f32x16 s_cur, s_nxt;
    {  // QK(jt=0)
      const int j = ql, sw = j & 7;
      __builtin_amdgcn_s_setprio(1);
      const f16x8 k0 = *(const f16x8*)(&Ks[cur][j * 64 + ((hi ^ sw) << 3)]);
      s_cur = MFMA32(k0, qf[0], initv);
#pragma unroll
      for (int kc = 1; kc < 4; kc++) {
        const f16x8 kf = *(const f16x8*)(&Ks[cur][j * 64 + ((((kc << 1) | hi) ^ sw) << 3)]);
        s_cur = MFMA32(kf, qf[kc], s_cur);
      }
      __builtin_amdgcn_s_setprio(0);
    }

#pragma unroll
    for (int jt = 0; jt < 4; jt++) {
      // issue QK(jt+1) — overlaps the softmax VALU below
      if (jt < 3) {
        const int j = (jt + 1) * 32 + ql, sw = j & 7;
        const f16x8 k0 = *(const f16x8*)(&Ks[cur][j * 64 + ((hi ^ sw) << 3)]);
        s_nxt = MFMA32(k0, qf[0], initv);
#pragma unroll
        for (int kc = 1; kc < 4; kc++) {
          const f16x8 kf = *(const f16x8*)(&Ks[cur][j * 64 + ((((kc << 1) | hi) ^ sw) << 3)]);
          s_nxt = MFMA32(kf, qf[kc], s_nxt);
        }
      }

      // softmax on s_cur: exp2 -> pack -> fdot2 rowsum (2 chains)
      int w[8];
#pragma unroll
      for (int m = 0; m < 8; m++) {
        const float pa = __builtin_amdgcn_exp2f(s_cur[2 * m]);
        const float pb = __builtin_amdgcn_exp2f(s_cur[2 * m + 1]);
        const auto h = __builtin_amdgcn_cvt_pkrtz(pa, pb);
        if (m & 1)
          rsum1 = __builtin_amdgcn_fdot2(h, one2, rsum1, false);
        else
          rsum0 = __builtin_amdgcn_fdot2(h, one2, rsum0, false);
        w[m] = __builtin_bit_cast(int, h);
      }
#pragma unroll
      for (int kl = 0; kl < 2; kl++) {
        int a0 = w[4 * kl + 0], a1 = w[4 * kl + 1];
        int a2 = w[4 * kl + 2], a3 = w[4 * kl + 3];
        // v_permlane32_swap: dst.hi32lanes <-> src.lo32lanes
        asm volatile("v_permlane32_swap_b32 %0, %1" : "+v"(a0), "+v"(a2));
        asm volatile("v_permlane32_swap_b32 %0, %1" : "+v"(a1), "+v"(a3));
        i32x4 fi = {a0, a1, a2, a3};
        const f16x8 pfrag = __builtin_bit_cast(f16x8, fi);
        const int kb = jt * 2 + kl;
        __builtin_amdgcn_s_setprio(1);
#pragma unroll
        for (int dt = 0; dt < 2; dt++) {
          const int d = dt * 32 + ql;
          const f16x8 vf =
              *(const f16x8*)(&Vs[cur][d * 128 + ((((kb << 1) | hi) ^ (d & 15)) << 3)]);
          oacc[kl][dt] = MFMA32(pfrag, vf, oacc[kl][dt]);
        }
        __builtin_amdgcn_s_setprio(0);
      }
      if (jt < 3) s_cur = s_nxt;
    }

    __syncthreads();  // drains prefetch vmcnt + all waves done with buf[cur]
  }

  // final rowsum (other hi-half holds complementary j's), divide, store
  float rsum = rsum0 + rsum1;
  rsum += __shfl_xor(rsum, 32);
  const int bb = bh >> 3, hh = bh & 7;
#pragma unroll
  for (int r = 0; r < 16; r++) {
    const int qloc = (r & 3) + 8 * (r >> 2) + 4 * hi;
    const float sm = __shfl(rsum, qloc);                // rowsum for q0w+qloc
    const float inv = 1.f / fmaxf(sm, 0.016384f);       // 1e-6 * 2^14
    f16* dst = Ob + (((long)(bb * 4096 + q0w + qloc)) << 9) + hh * 64;
    dst[ql] = (f16)((oacc[0][0][r] + oacc[1][0][r]) * inv);
    dst[32 + ql] = (f16)((oacc[0][1][r] + oacc[1][1][r]) * inv);
  }
}

// ---------------------------------------------------------------------------
extern "C" void kernel_launch(void* const* d_in, const int* in_sizes, int n_in,
                              void* d_out, int out_size, void* d_ws, size_t ws_size,
                              hipStream_t stream) {
  const float* x   = (const float*)d_in[0];   // [2,4096,1024]
  const float* Wq  = (const float*)d_in[1];   // [1024,512]
  const float* Wkv = (const float*)d_in[2];   // [1024,1024]
  const float* Wo  = (const float*)d_in[3];   // [512,1024]
  float* out = (float*)d_out;                 // [2,4096,1024] fp32

  char* ws = (char*)d_ws;
  f16* Vt     = (f16*)(ws);                   //  8.39 MB  [16][64][4096]
  f16* Wqkv_t = (f16*)(ws + 16777216);        //  3.15 MB  [1536][1024]
  f16* Wo_t   = (f16*)(ws + 19922944);        //  1.05 MB  [1024][512]
  f16* Qb     = (f16*)(ws + 20971520);        //  8.39 MB  [16][4096][64]
  f16* Kb     = (f16*)(ws + 29360128);        //  8.39 MB
  f16* At     = (f16*)(ws + 46137344);        //  8.39 MB  [8192][512]

  // all weight transposes in one launch
  transpose_all_kernel<<<dim3(16, 16, 4), dim3(64, 8), 0, stream>>>(Wq, Wkv, Wo, Wqkv_t, Wo_t);

  // fused x-convert + QKV projection + l2norm (+Q prescale) + V-transpose:
  // [8192 x 1536 x 1024]
  gemm_kernel<1><<<768, 256, 0, stream>>>(nullptr, Wqkv_t, nullptr, Qb, Kb, Vt, x,
                                          8192, 1536, 1024);
  // attention (512 blocks, XCD-decoded inside)
  attn_kernel<<<512, 256, 0, stream>>>(Qb, Kb, Vt, At, 4096);
  // output projection: [8192 x 1024 x 512]
  gemm_kernel<0><<<512, 256, 0, stream>>>(At, Wo_t, out, nullptr, nullptr, nullptr, nullptr,
                                          8192, 1024, 512);
}

// Round 15
// 148.085 us; speedup vs baseline: 1.3434x; 1.0095x over previous
//
#include <hip/hip_runtime.h>

// ---------------------------------------------------------------------------
// FlashAttention_45844480917693 — cosine-sim attention, MI355X (gfx950)
// R15: attn rowsum moved from VALU (fdot2 + epilogue shuffles) into the MFMA
// pipe via ones-B MFMA (osum accumulates full rowsum per lane; no cross-lane
// reduction left). Rest = R14: fused x-convert QKV GEMM + fused V-transpose
// epilogue, merged weight transposes, XCD-local decode, R8 attn schedule,
// register P via permlane32_swap.
// ---------------------------------------------------------------------------

typedef _Float16 f16;
typedef _Float16 f16x4 __attribute__((ext_vector_type(4)));
typedef _Float16 f16x8 __attribute__((ext_vector_type(8)));
typedef float f32x4 __attribute__((ext_vector_type(4)));
typedef float f32x16 __attribute__((ext_vector_type(16)));
typedef int i32x4 __attribute__((ext_vector_type(4)));

#define MFMA_F16(a, b, c) __builtin_amdgcn_mfma_f32_16x16x32_f16((a), (b), (c), 0, 0, 0)
#define MFMA32(a, b, c) __builtin_amdgcn_mfma_f32_32x32x16_f16((a), (b), (c), 0, 0, 0)

// 16 * log2(e)
#define QSCALE 23.083120654223414f
// exp2 bias: -QSCALE + 14 (P pre-scaled by 2^14, cancels in rowsum division)
#define EXPBIAS -9.083120654223414f

__device__ __forceinline__ void gl_lds16(const void* g, void* l) {
  // async global->LDS, 16B per lane; LDS dest = wave-uniform base + lane*16
  __builtin_amdgcn_global_load_lds(
      (const __attribute__((address_space(1))) void*)g,
      (__attribute__((address_space(3))) void*)l, 16, 0, 0);
}

// ---------------------------------------------------------------------------
// All weight transposes in one launch. z selects {Wq, Wkv-lo, Wkv-hi, Wo}.
__global__ void transpose_all_kernel(const float* __restrict__ Wq,
                                     const float* __restrict__ Wkv,
                                     const float* __restrict__ Wo,
                                     f16* __restrict__ Wqkv_t, f16* __restrict__ Wo_t) {
  __shared__ float t[64][65];
  const int z = blockIdx.z;
  const float* W; int ldw, col0, K, nc; f16* out;
  if (z == 0)      { W = Wq;  ldw = 512;  col0 = 0;   K = 1024; nc = 8;  out = Wqkv_t; }
  else if (z == 1) { W = Wkv; ldw = 1024; col0 = 0;   K = 1024; nc = 8;  out = Wqkv_t + 512 * 1024; }
  else if (z == 2) { W = Wkv; ldw = 1024; col0 = 512; K = 1024; nc = 8;  out = Wqkv_t + 1024 * 1024; }
  else             { W = Wo;  ldw = 1024; col0 = 0;   K = 512;  nc = 16; out = Wo_t; }
  if ((int)blockIdx.x >= nc || (int)blockIdx.y >= (K >> 6)) return;
  int tx = threadIdx.x, ty = threadIdx.y;
  int c0 = blockIdx.x * 64, k0 = blockIdx.y * 64;
#pragma unroll
  for (int i = 0; i < 8; i++)
    t[ty + i * 8][tx] = W[(long)(k0 + ty + i * 8) * ldw + col0 + c0 + tx];
  __syncthreads();
#pragma unroll
  for (int i = 0; i < 8; i++)
    out[(long)(c0 + ty + i * 8) * K + k0 + tx] = (f16)t[tx][ty + i * 8];
}

// ---------------------------------------------------------------------------
// GEMM: C[M][N] = A[M][K] * Bt[N][K]^T, 128x128 tile, BK=32, 4 waves (2x2).
// MODE 0: A fp16 via gl_lds, fp32 C out.
// MODE 1: A = x fp32, reg-staged + converted to fp16 in-register; fused QKV
//         epilogue: Q/K l2norm (+Q prescale) direct store; V written
//         TRANSPOSED to Vt[bh][d][n] via padded-LDS bounce (coalesced).
template <int MODE>
__global__ __launch_bounds__(256, 3)
void gemm_kernel(const f16* __restrict__ A, const f16* __restrict__ Bt,
                 float* __restrict__ C,
                 f16* __restrict__ Qb, f16* __restrict__ Kb, f16* __restrict__ Vtb,
                 const float* __restrict__ Axf,
                 int M, int N, int K) {
  __shared__ f16 As[128 * 32];
  __shared__ f16 Bs[128 * 32];
  const int tid = threadIdx.x;
  const int lane = tid & 63;
  const int wid = tid >> 6;
  const int wr = wid >> 1, wc = wid & 1;
  const int lr = lane & 15, lk = lane >> 4;
  const int lin = blockIdx.x;
  const int bx = ((lin & 7) << 3) | ((lin >> 3) & 7);  // XCD (lin%8) owns 8 x-panels
  const int by = lin >> 6;
  const long m0 = (long)bx * 128;
  const int n0 = by * 128;

  f32x4 acc[4][4] = {};

  const int c0 = tid, c1 = tid + 256;
  const int ar0 = c0 >> 2, ah0 = (c0 & 3) ^ ((ar0 >> 1) & 3);
  const int ar1 = c1 >> 2, ah1 = (c1 & 3) ^ ((ar1 >> 1) & 3);
  const f16* pa0 = A + (m0 + ar0) * K + ah0 * 8;
  const f16* pa1 = A + (m0 + ar1) * K + ah1 * 8;
  const float* pa0f = Axf + (m0 + ar0) * K + ah0 * 8;
  const float* pa1f = Axf + (m0 + ar1) * K + ah1 * 8;
  const f16* pb0 = Bt + (long)(n0 + ar0) * K + ah0 * 8;
  const f16* pb1 = Bt + (long)(n0 + ar1) * K + ah1 * 8;

  // MODE 1: A-tile registers (8 fp32 per chunk, 2 chunks)
  float4 a00, a01, a10, a11;
  if (MODE == 1) {
    a00 = *(const float4*)(pa0f);
    a01 = *(const float4*)(pa0f + 4);
    a10 = *(const float4*)(pa1f);
    a11 = *(const float4*)(pa1f + 4);
  }

  for (int k0 = 0; k0 < K; k0 += 32) {
    __syncthreads();          // previous tile fully consumed
    if (MODE == 1) {
      f16x8 w0, w1;
#pragma unroll
      for (int e = 0; e < 4; e++) {
        w0[e] = (f16)(&a00.x)[e];
        w0[4 + e] = (f16)(&a01.x)[e];
        w1[e] = (f16)(&a10.x)[e];
        w1[4 + e] = (f16)(&a11.x)[e];
      }
      *(f16x8*)(As + c0 * 8) = w0;
      *(f16x8*)(As + c1 * 8) = w1;
    } else {
      gl_lds16(pa0 + k0, As + c0 * 8);
      gl_lds16(pa1 + k0, As + c1 * 8);
    }
    gl_lds16(pb0 + k0, Bs + c0 * 8);
    gl_lds16(pb1 + k0, Bs + c1 * 8);
    __syncthreads();          // staging complete (drains vmcnt + lgkmcnt)

    // issue next A-tile loads — latency hidden under the MFMA phase below
    if (MODE == 1 && k0 + 32 < K) {
      a00 = *(const float4*)(pa0f + k0 + 32);
      a01 = *(const float4*)(pa0f + k0 + 36);
      a10 = *(const float4*)(pa1f + k0 + 32);
      a11 = *(const float4*)(pa1f + k0 + 36);
    }

    f16x8 af[4], bf[4];
#pragma unroll
    for (int mi = 0; mi < 4; mi++) {
      int row = wr * 64 + mi * 16 + lr;
      int ch = lk ^ ((row >> 1) & 3);
      af[mi] = *(const f16x8*)(As + row * 32 + ch * 8);
    }
#pragma unroll
    for (int ni = 0; ni < 4; ni++) {
      int row = wc * 64 + ni * 16 + lr;
      int ch = lk ^ ((row >> 1) & 3);
      bf[ni] = *(const f16x8*)(Bs + row * 32 + ch * 8);
    }
    __builtin_amdgcn_s_setprio(1);
#pragma unroll
    for (int mi = 0; mi < 4; mi++)
#pragma unroll
      for (int ni = 0; ni < 4; ni++)
        acc[mi][ni] = MFMA_F16(af[mi], bf[ni], acc[mi][ni]);
    __builtin_amdgcn_s_setprio(0);
  }

  if constexpr (MODE == 0) {
#pragma unroll
    for (int mi = 0; mi < 4; mi++) {
      long mrow = m0 + wr * 64 + mi * 16 + lk * 4;
#pragma unroll
      for (int r = 0; r < 4; r++)
#pragma unroll
        for (int ni = 0; ni < 4; ni++)
          C[(mrow + r) * N + n0 + wc * 64 + ni * 16 + lr] = acc[mi][ni][r];
    }
  } else {
    const int region = by >> 2;                      // 0=Q, 1=K, 2=V
    if (region < 2) {
      const int head = (by & 3) * 2 + wc;
      f16* buf = (region == 0) ? Qb : Kb;
      const float nscale = (region == 0) ? QSCALE : 1.f;  // Q pre-scaled
#pragma unroll
      for (int mi = 0; mi < 4; mi++) {
        float scl[4];
#pragma unroll
        for (int r = 0; r < 4; r++) {
          float s2 = 0.f;
#pragma unroll
          for (int ni = 0; ni < 4; ni++) s2 += acc[mi][ni][r] * acc[mi][ni][r];
          s2 += __shfl_xor(s2, 1);
          s2 += __shfl_xor(s2, 2);
          s2 += __shfl_xor(s2, 4);
          s2 += __shfl_xor(s2, 8);
          scl[r] = nscale / fmaxf(sqrtf(s2), 1e-12f);
        }
#pragma unroll
        for (int r = 0; r < 4; r++) {
          int m = (int)m0 + wr * 64 + mi * 16 + lk * 4 + r;
          int bb = m >> 12, nn = m & 4095;
          f16* dst = buf + (((long)(bb * 8 + head) * 4096 + nn) << 6);
#pragma unroll
          for (int ni = 0; ni < 4; ni++)
            dst[ni * 16 + lr] = (f16)(acc[mi][ni][r] * scl[r]);
        }
      }
    } else {
      // V region: write transposed to Vt[bh][d][n] via padded LDS bounce.
      __shared__ f16 Ts[128 * 136];   // [row n_local][col], pad -> 272B rows
#pragma unroll
      for (int mi = 0; mi < 4; mi++)
#pragma unroll
        for (int r = 0; r < 4; r++) {
          const int row = wr * 64 + mi * 16 + lk * 4 + r;
#pragma unroll
          for (int ni = 0; ni < 4; ni++)
            Ts[row * 136 + wc * 64 + ni * 16 + lr] = (f16)acc[mi][ni][r];
        }
      __syncthreads();
      const int bb = (int)(m0 >> 12), nloc0 = (int)(m0 & 4095);
#pragma unroll
      for (int i = 0; i < 8; i++) {
        const int chunk = tid + i * 256;         // 2048 chunks: [r128][cc]
        const int r128 = chunk >> 4, cc = chunk & 15;
        const int head2 = (by & 3) * 2 + (r128 >> 6), d = r128 & 63;
        f16x8 v;
#pragma unroll
        for (int e = 0; e < 8; e++) v[e] = Ts[(cc * 8 + e) * 136 + r128];
        *(f16x8*)(Vtb + (((long)((bb * 8 + head2) * 64 + d)) << 12) + nloc0 + cc * 8) = v;
      }
    }
  }
}

// ---------------------------------------------------------------------------
// Attention: 32x32x16 MFMA, 4 waves x 32 q, KVBLK=128, K+V double-buffered
// (64 KB), one barrier/tile, QK(jt+1)/softmax(jt) software pipeline, register
// P via permlane32_swap. Rowsum via ones-B MFMA (osum) — MFMA K-reduction
// spans both hi-halves, so NO cross-lane reduction in the epilogue.
__global__ __launch_bounds__(256, 2)
void attn_kernel(const f16* __restrict__ Qb, const f16* __restrict__ Kb,
                 const f16* __restrict__ Vt, f16* __restrict__ Ob, int n) {
  __shared__ f16 Ks[2][128 * 64];    // [j][d], 16B-chunk ^= (j&7)   16KB x2
  __shared__ f16 Vs[2][64 * 128];    // [d][j], 16B-chunk ^= (d&15)  16KB x2
  const int tid = threadIdx.x, lane = tid & 63, wid = tid >> 6;  // wid 0..3
  const int ql = lane & 31, hi = lane >> 5;
  const int lin = blockIdx.x;
  const int bh = (lin & 7) | ((lin >> 8) << 3);
  const int qx = (lin >> 3) & 31;
  const long nl = n;
  const f16* Qg = Qb + (long)bh * nl * 64;
  const f16* Kg = Kb + (long)bh * nl * 64;
  const f16* Vg = Vt + (long)bh * 64 * nl;
  const int q0w = qx * 128 + wid * 32;

  // Q fragments (B-operand): col q = ql, k d = kc*16 + hi*8 + e
  f16x8 qf[4];
#pragma unroll
  for (int kc = 0; kc < 4; kc++)
    qf[kc] = *(const f16x8*)(Qg + (long)(q0w + ql) * 64 + kc * 16 + hi * 8);

  // staging source offsets (4 K-chunks + 4 V-chunks per thread per tile);
  // LDS dest stays lane-linear, source pre-swizzled.
  int ksrc[4], vsrc[4];
#pragma unroll
  for (int p = 0; p < 4; p++) {
    const int ci = tid + p * 256;
    const int kj = ci >> 3, kc_ = ci & 7;
    ksrc[p] = kj * 64 + ((kc_ ^ (kj & 7)) << 3);
    const int vd = ci >> 4, vc = ci & 15;
    vsrc[p] = vd * n + ((vc ^ (vd & 15)) << 3);
  }

  f32x16 oacc[2][2] = {};   // [kl][dt] — 4 independent MFMA chains
  f32x16 osum = {};         // rowsum accumulator (ones-B MFMA)
  f32x16 initv;
#pragma unroll
  for (int e = 0; e < 16; e++) initv[e] = EXPBIAS;
  f16x8 onesb;
#pragma unroll
  for (int e = 0; e < 8; e++) onesb[e] = (f16)1.f;

  // prologue: stage tile 0 into buf 0
#pragma unroll
  for (int p = 0; p < 4; p++) {
    gl_lds16(Kg + ksrc[p], &Ks[0][(tid + p * 256) * 8]);
    gl_lds16(Vg + vsrc[p], &Vs[0][(tid + p * 256) * 8]);
  }
  __syncthreads();

  const int nt = n >> 7;
  for (int t = 0; t < nt; t++) {
    const int cur = t & 1;
    if (t + 1 < nt) {
      const long kadv = (long)(t + 1) * 8192;   // 128 rows * 64 d
      const long vadv = (long)(t + 1) * 128;    // +128 j
#pragma unroll
      for (int p = 0; p < 4; p++) {
        gl_lds16(Kg + kadv + ksrc[p], &Ks[cur ^ 1][(tid + p * 256) * 8]);
        gl_lds16(Vg + vadv + vsrc[p], &Vs[cur ^ 1][(tid + p * 256) * 8]);
      }
    }

    // ---- software pipeline over 32-j sub-tiles ----
    f32x16 s_cur, s_nxt;
    {  // QK(jt=0)
      const int j = ql, sw = j & 7;
      __builtin_amdgcn_s_setprio(1);
      const f16x8 k0 = *(const f16x8*)(&Ks[cur][j * 64 + ((hi ^ sw) << 3)]);
      s_cur = MFMA32(k0, qf[0], initv);
#pragma unroll
      for (int kc = 1; kc < 4; kc++) {
        const f16x8 kf = *(const f16x8*)(&Ks[cur][j * 64 + ((((kc << 1) | hi) ^ sw) << 3)]);
        s_cur = MFMA32(kf, qf[kc], s_cur);
      }
      __builtin_amdgcn_s_setprio(0);
    }

#pragma unroll
    for (int jt = 0; jt < 4; jt++) {
      // issue QK(jt+1) — overlaps the softmax VALU below
      if (jt < 3) {
        const int j = (jt + 1) * 32 + ql, sw = j & 7;
        const f16x8 k0 = *(const f16x8*)(&Ks[cur][j * 64 + ((hi ^ sw) << 3)]);
        s_nxt = MFMA32(k0, qf[0], initv);
#pragma unroll
        for (int kc = 1; kc < 4; kc++) {
          const f16x8 kf = *(const f16x8*)(&Ks[cur][j * 64 + ((((kc << 1) | hi) ^ sw) << 3)]);
          s_nxt = MFMA32(kf, qf[kc], s_nxt);
        }
      }

      // softmax on s_cur: exp2 -> pack (rowsum handled by ones-MFMA below)
      int w[8];
#pragma unroll
      for (int m = 0; m < 8; m++) {
        const float pa = __builtin_amdgcn_exp2f(s_cur[2 * m]);
        const float pb = __builtin_amdgcn_exp2f(s_cur[2 * m + 1]);
        const auto h = __builtin_amdgcn_cvt_pkrtz(pa, pb);
        w[m] = __builtin_bit_cast(int, h);
      }
#pragma unroll
      for (int kl = 0; kl < 2; kl++) {
        int a0 = w[4 * kl + 0], a1 = w[4 * kl + 1];
        int a2 = w[4 * kl + 2], a3 = w[4 * kl + 3];
        // v_permlane32_swap: dst.hi32lanes <-> src.lo32lanes
        asm volatile("v_permlane32_swap_b32 %0, %1" : "+v"(a0), "+v"(a2));
        asm volatile("v_permlane32_swap_b32 %0, %1" : "+v"(a1), "+v"(a3));
        i32x4 fi = {a0, a1, a2, a3};
        const f16x8 pfrag = __builtin_bit_cast(f16x8, fi);
        const int kb = jt * 2 + kl;
        __builtin_amdgcn_s_setprio(1);
        osum = MFMA32(pfrag, onesb, osum);           // rowsum in MFMA pipe
#pragma unroll
        for (int dt = 0; dt < 2; dt++) {
          const int d = dt * 32 + ql;
          const f16x8 vf =
              *(const f16x8*)(&Vs[cur][d * 128 + ((((kb << 1) | hi) ^ (d & 15)) << 3)]);
          oacc[kl][dt] = MFMA32(pfrag, vf, oacc[kl][dt]);
        }
        __builtin_amdgcn_s_setprio(0);
      }
      if (jt < 3) s_cur = s_nxt;
    }

    __syncthreads();  // drains prefetch vmcnt + all waves done with buf[cur]
  }

  // osum[r] = full rowsum for q-row qloc(r) (duplicated across d-lanes);
  // no cross-lane reduction needed. Divide and store.
  const int bb = bh >> 3, hh = bh & 7;
#pragma unroll
  for (int r = 0; r < 16; r++) {
    const int qloc = (r & 3) + 8 * (r >> 2) + 4 * hi;
    const float inv = 1.f / fmaxf(osum[r], 0.016384f);  // 1e-6 * 2^14
    f16* dst = Ob + (((long)(bb * 4096 + q0w + qloc)) << 9) + hh * 64;
    dst[ql] = (f16)((oacc[0][0][r] + oacc[1][0][r]) * inv);
    dst[32 + ql] = (f16)((oacc[0][1][r] + oacc[1][1][r]) * inv);
  }
}

// ---------------------------------------------------------------------------
extern "C" void kernel_launch(void* const* d_in, const int* in_sizes, int n_in,
                              void* d_out, int out_size, void* d_ws, size_t ws_size,
                              hipStream_t stream) {
  const float* x   = (const float*)d_in[0];   // [2,4096,1024]
  const float* Wq  = (const float*)d_in[1];   // [1024,512]
  const float* Wkv = (const float*)d_in[2];   // [1024,1024]
  const float* Wo  = (const float*)d_in[3];   // [512,1024]
  float* out = (float*)d_out;                 // [2,4096,1024] fp32

  char* ws = (char*)d_ws;
  f16* Vt     = (f16*)(ws);                   //  8.39 MB  [16][64][4096]
  f16* Wqkv_t = (f16*)(ws + 16777216);        //  3.15 MB  [1536][1024]
  f16* Wo_t   = (f16*)(ws + 19922944);        //  1.05 MB  [1024][512]
  f16* Qb     = (f16*)(ws + 20971520);        //  8.39 MB  [16][4096][64]
  f16* Kb     = (f16*)(ws + 29360128);        //  8.39 MB
  f16* At     = (f16*)(ws + 46137344);        //  8.39 MB  [8192][512]

  // all weight transposes in one launch
  transpose_all_kernel<<<dim3(16, 16, 4), dim3(64, 8), 0, stream>>>(Wq, Wkv, Wo, Wqkv_t, Wo_t);

  // fused x-convert + QKV projection + l2norm (+Q prescale) + V-transpose:
  // [8192 x 1536 x 1024]
  gemm_kernel<1><<<768, 256, 0, stream>>>(nullptr, Wqkv_t, nullptr, Qb, Kb, Vt, x,
                                          8192, 1536, 1024);
  // attention (512 blocks, XCD-decoded inside)
  attn_kernel<<<512, 256, 0, stream>>>(Qb, Kb, Vt, At, 4096);
  // output projection: [8192 x 1024 x 512]
  gemm_kernel<0><<<512, 256, 0, stream>>>(At, Wo_t, out, nullptr, nullptr, nullptr, nullptr,
                                          8192, 1024, 512);
}

// Round 16
// 147.271 us; speedup vs baseline: 1.3508x; 1.0055x over previous
//
#include <hip/hip_runtime.h>

// ---------------------------------------------------------------------------
// FlashAttention_45844480917693 — cosine-sim attention, MI355X (gfx950)
// R16: attn issue-count trim — ones-MFMA halved (8->4/tile) by v_pk_add_f16
// of the two kl P-fragments before the rowsum MFMA; setprio toggles thinned
// to one pair per jt MFMA cluster. Rest = R15: fused x-convert QKV GEMM +
// fused V-transpose epilogue, merged weight transposes, XCD-local decode,
// R8 attn schedule, register P via permlane32_swap, ones-MFMA rowsum.
// ---------------------------------------------------------------------------

typedef _Float16 f16;
typedef _Float16 f16x4 __attribute__((ext_vector_type(4)));
typedef _Float16 f16x8 __attribute__((ext_vector_type(8)));
typedef float f32x4 __attribute__((ext_vector_type(4)));
typedef float f32x16 __attribute__((ext_vector_type(16)));
typedef int i32x4 __attribute__((ext_vector_type(4)));

#define MFMA_F16(a, b, c) __builtin_amdgcn_mfma_f32_16x16x32_f16((a), (b), (c), 0, 0, 0)
#define MFMA32(a, b, c) __builtin_amdgcn_mfma_f32_32x32x16_f16((a), (b), (c), 0, 0, 0)

// 16 * log2(e)
#define QSCALE 23.083120654223414f
// exp2 bias: -QSCALE + 14 (P pre-scaled by 2^14, cancels in rowsum division)
#define EXPBIAS -9.083120654223414f

__device__ __forceinline__ void gl_lds16(const void* g, void* l) {
  // async global->LDS, 16B per lane; LDS dest = wave-uniform base + lane*16
  __builtin_amdgcn_global_load_lds(
      (const __attribute__((address_space(1))) void*)g,
      (__attribute__((address_space(3))) void*)l, 16, 0, 0);
}

// ---------------------------------------------------------------------------
// All weight transposes in one launch. z selects {Wq, Wkv-lo, Wkv-hi, Wo}.
__global__ void transpose_all_kernel(const float* __restrict__ Wq,
                                     const float* __restrict__ Wkv,
                                     const float* __restrict__ Wo,
                                     f16* __restrict__ Wqkv_t, f16* __restrict__ Wo_t) {
  __shared__ float t[64][65];
  const int z = blockIdx.z;
  const float* W; int ldw, col0, K, nc; f16* out;
  if (z == 0)      { W = Wq;  ldw = 512;  col0 = 0;   K = 1024; nc = 8;  out = Wqkv_t; }
  else if (z == 1) { W = Wkv; ldw = 1024; col0 = 0;   K = 1024; nc = 8;  out = Wqkv_t + 512 * 1024; }
  else if (z == 2) { W = Wkv; ldw = 1024; col0 = 512; K = 1024; nc = 8;  out = Wqkv_t + 1024 * 1024; }
  else             { W = Wo;  ldw = 1024; col0 = 0;   K = 512;  nc = 16; out = Wo_t; }
  if ((int)blockIdx.x >= nc || (int)blockIdx.y >= (K >> 6)) return;
  int tx = threadIdx.x, ty = threadIdx.y;
  int c0 = blockIdx.x * 64, k0 = blockIdx.y * 64;
#pragma unroll
  for (int i = 0; i < 8; i++)
    t[ty + i * 8][tx] = W[(long)(k0 + ty + i * 8) * ldw + col0 + c0 + tx];
  __syncthreads();
#pragma unroll
  for (int i = 0; i < 8; i++)
    out[(long)(c0 + ty + i * 8) * K + k0 + tx] = (f16)t[tx][ty + i * 8];
}

// ---------------------------------------------------------------------------
// GEMM: C[M][N] = A[M][K] * Bt[N][K]^T, 128x128 tile, BK=32, 4 waves (2x2).
// MODE 0: A fp16 via gl_lds, fp32 C out.
// MODE 1: A = x fp32, reg-staged + converted to fp16 in-register; fused QKV
//         epilogue: Q/K l2norm (+Q prescale) direct store; V written
//         TRANSPOSED to Vt[bh][d][n] via padded-LDS bounce (coalesced).
template <int MODE>
__global__ __launch_bounds__(256, 3)
void gemm_kernel(const f16* __restrict__ A, const f16* __restrict__ Bt,
                 float* __restrict__ C,
                 f16* __restrict__ Qb, f16* __restrict__ Kb, f16* __restrict__ Vtb,
                 const float* __restrict__ Axf,
                 int M, int N, int K) {
  __shared__ f16 As[128 * 32];
  __shared__ f16 Bs[128 * 32];
  const int tid = threadIdx.x;
  const int lane = tid & 63;
  const int wid = tid >> 6;
  const int wr = wid >> 1, wc = wid & 1;
  const int lr = lane & 15, lk = lane >> 4;
  const int lin = blockIdx.x;
  const int bx = ((lin & 7) << 3) | ((lin >> 3) & 7);  // XCD (lin%8) owns 8 x-panels
  const int by = lin >> 6;
  const long m0 = (long)bx * 128;
  const int n0 = by * 128;

  f32x4 acc[4][4] = {};

  const int c0 = tid, c1 = tid + 256;
  const int ar0 = c0 >> 2, ah0 = (c0 & 3) ^ ((ar0 >> 1) & 3);
  const int ar1 = c1 >> 2, ah1 = (c1 & 3) ^ ((ar1 >> 1) & 3);
  const f16* pa0 = A + (m0 + ar0) * K + ah0 * 8;
  const f16* pa1 = A + (m0 + ar1) * K + ah1 * 8;
  const float* pa0f = Axf + (m0 + ar0) * K + ah0 * 8;
  const float* pa1f = Axf + (m0 + ar1) * K + ah1 * 8;
  const f16* pb0 = Bt + (long)(n0 + ar0) * K + ah0 * 8;
  const f16* pb1 = Bt + (long)(n0 + ar1) * K + ah1 * 8;

  // MODE 1: A-tile registers (8 fp32 per chunk, 2 chunks)
  float4 a00, a01, a10, a11;
  if (MODE == 1) {
    a00 = *(const float4*)(pa0f);
    a01 = *(const float4*)(pa0f + 4);
    a10 = *(const float4*)(pa1f);
    a11 = *(const float4*)(pa1f + 4);
  }

  for (int k0 = 0; k0 < K; k0 += 32) {
    __syncthreads();          // previous tile fully consumed
    if (MODE == 1) {
      f16x8 w0, w1;
#pragma unroll
      for (int e = 0; e < 4; e++) {
        w0[e] = (f16)(&a00.x)[e];
        w0[4 + e] = (f16)(&a01.x)[e];
        w1[e] = (f16)(&a10.x)[e];
        w1[4 + e] = (f16)(&a11.x)[e];
      }
      *(f16x8*)(As + c0 * 8) = w0;
      *(f16x8*)(As + c1 * 8) = w1;
    } else {
      gl_lds16(pa0 + k0, As + c0 * 8);
      gl_lds16(pa1 + k0, As + c1 * 8);
    }
    gl_lds16(pb0 + k0, Bs + c0 * 8);
    gl_lds16(pb1 + k0, Bs + c1 * 8);
    __syncthreads();          // staging complete (drains vmcnt + lgkmcnt)

    // issue next A-tile loads — latency hidden under the MFMA phase below
    if (MODE == 1 && k0 + 32 < K) {
      a00 = *(const float4*)(pa0f + k0 + 32);
      a01 = *(const float4*)(pa0f + k0 + 36);
      a10 = *(const float4*)(pa1f + k0 + 32);
      a11 = *(const float4*)(pa1f + k0 + 36);
    }

    f16x8 af[4], bf[4];
#pragma unroll
    for (int mi = 0; mi < 4; mi++) {
      int row = wr * 64 + mi * 16 + lr;
      int ch = lk ^ ((row >> 1) & 3);
      af[mi] = *(const f16x8*)(As + row * 32 + ch * 8);
    }
#pragma unroll
    for (int ni = 0; ni < 4; ni++) {
      int row = wc * 64 + ni * 16 + lr;
      int ch = lk ^ ((row >> 1) & 3);
      bf[ni] = *(const f16x8*)(Bs + row * 32 + ch * 8);
    }
    __builtin_amdgcn_s_setprio(1);
#pragma unroll
    for (int mi = 0; mi < 4; mi++)
#pragma unroll
      for (int ni = 0; ni < 4; ni++)
        acc[mi][ni] = MFMA_F16(af[mi], bf[ni], acc[mi][ni]);
    __builtin_amdgcn_s_setprio(0);
  }

  if constexpr (MODE == 0) {
#pragma unroll
    for (int mi = 0; mi < 4; mi++) {
      long mrow = m0 + wr * 64 + mi * 16 + lk * 4;
#pragma unroll
      for (int r = 0; r < 4; r++)
#pragma unroll
        for (int ni = 0; ni < 4; ni++)
          C[(mrow + r) * N + n0 + wc * 64 + ni * 16 + lr] = acc[mi][ni][r];
    }
  } else {
    const int region = by >> 2;                      // 0=Q, 1=K, 2=V
    if (region < 2) {
      const int head = (by & 3) * 2 + wc;
      f16* buf = (region == 0) ? Qb : Kb;
      const float nscale = (region == 0) ? QSCALE : 1.f;  // Q pre-scaled
#pragma unroll
      for (int mi = 0; mi < 4; mi++) {
        float scl[4];
#pragma unroll
        for (int r = 0; r < 4; r++) {
          float s2 = 0.f;
#pragma unroll
          for (int ni = 0; ni < 4; ni++) s2 += acc[mi][ni][r] * acc[mi][ni][r];
          s2 += __shfl_xor(s2, 1);
          s2 += __shfl_xor(s2, 2);
          s2 += __shfl_xor(s2, 4);
          s2 += __shfl_xor(s2, 8);
          scl[r] = nscale / fmaxf(sqrtf(s2), 1e-12f);
        }
#pragma unroll
        for (int r = 0; r < 4; r++) {
          int m = (int)m0 + wr * 64 + mi * 16 + lk * 4 + r;
          int bb = m >> 12, nn = m & 4095;
          f16* dst = buf + (((long)(bb * 8 + head) * 4096 + nn) << 6);
#pragma unroll
          for (int ni = 0; ni < 4; ni++)
            dst[ni * 16 + lr] = (f16)(acc[mi][ni][r] * scl[r]);
        }
      }
    } else {
      // V region: write transposed to Vt[bh][d][n] via padded LDS bounce.
      __shared__ f16 Ts[128 * 136];   // [row n_local][col], pad -> 272B rows
#pragma unroll
      for (int mi = 0; mi < 4; mi++)
#pragma unroll
        for (int r = 0; r < 4; r++) {
          const int row = wr * 64 + mi * 16 + lk * 4 + r;
#pragma unroll
          for (int ni = 0; ni < 4; ni++)
            Ts[row * 136 + wc * 64 + ni * 16 + lr] = (f16)acc[mi][ni][r];
        }
      __syncthreads();
      const int bb = (int)(m0 >> 12), nloc0 = (int)(m0 & 4095);
#pragma unroll
      for (int i = 0; i < 8; i++) {
        const int chunk = tid + i * 256;         // 2048 chunks: [r128][cc]
        const int r128 = chunk >> 4, cc = chunk & 15;
        const int head2 = (by & 3) * 2 + (r128 >> 6), d = r128 & 63;
        f16x8 v;
#pragma unroll
        for (int e = 0; e < 8; e++) v[e] = Ts[(cc * 8 + e) * 136 + r128];
        *(f16x8*)(Vtb + (((long)((bb * 8 + head2) * 64 + d)) << 12) + nloc0 + cc * 8) = v;
      }
    }
  }
}

// ---------------------------------------------------------------------------
// Attention: 32x32x16 MFMA, 4 waves x 32 q, KVBLK=128, K+V double-buffered
// (64 KB), one barrier/tile, QK(jt+1)/softmax(jt) software pipeline, register
// P via permlane32_swap. Rowsum via ONE ones-B MFMA per jt (kl fragments
// pre-summed with v_pk_add_f16) — no cross-lane reduction in the epilogue.
__global__ __launch_bounds__(256, 2)
void attn_kernel(const f16* __restrict__ Qb, const f16* __restrict__ Kb,
                 const f16* __restrict__ Vt, f16* __restrict__ Ob, int n) {
  __shared__ f16 Ks[2][128 * 64];    // [j][d], 16B-chunk ^= (j&7)   16KB x2
  __shared__ f16 Vs[2][64 * 128];    // [d][j], 16B-chunk ^= (d&15)  16KB x2
  const int tid = threadIdx.x, lane = tid & 63, wid = tid >> 6;  // wid 0..3
  const int ql = lane & 31, hi = lane >> 5;
  const int lin = blockIdx.x;
  const int bh = (lin & 7) | ((lin >> 8) << 3);
  const int qx = (lin >> 3) & 31;
  const long nl = n;
  const f16* Qg = Qb + (long)bh * nl * 64;
  const f16* Kg = Kb + (long)bh * nl * 64;
  const f16* Vg = Vt + (long)bh * 64 * nl;
  const int q0w = qx * 128 + wid * 32;

  // Q fragments (B-operand): col q = ql, k d = kc*16 + hi*8 + e
  f16x8 qf[4];
#pragma unroll
  for (int kc = 0; kc < 4; kc++)
    qf[kc] = *(const f16x8*)(Qg + (long)(q0w + ql) * 64 + kc * 16 + hi * 8);

  // staging source offsets (4 K-chunks + 4 V-chunks per thread per tile);
  // LDS dest stays lane-linear, source pre-swizzled.
  int ksrc[4], vsrc[4];
#pragma unroll
  for (int p = 0; p < 4; p++) {
    const int ci = tid + p * 256;
    const int kj = ci >> 3, kc_ = ci & 7;
    ksrc[p] = kj * 64 + ((kc_ ^ (kj & 7)) << 3);
    const int vd = ci >> 4, vc = ci & 15;
    vsrc[p] = vd * n + ((vc ^ (vd & 15)) << 3);
  }

  f32x16 oacc[2][2] = {};   // [kl][dt] — 4 independent MFMA chains
  f32x16 osum = {};         // rowsum accumulator (ones-B MFMA)
  f32x16 initv;
#pragma unroll
  for (int e = 0; e < 16; e++) initv[e] = EXPBIAS;
  f16x8 onesb;
#pragma unroll
  for (int e = 0; e < 8; e++) onesb[e] = (f16)1.f;

  // prologue: stage tile 0 into buf 0
#pragma unroll
  for (int p = 0; p < 4; p++) {
    gl_lds16(Kg + ksrc[p], &Ks[0][(tid + p * 256) * 8]);
    gl_lds16(Vg + vsrc[p], &Vs[0][(tid + p * 256) * 8]);
  }
  __syncthreads();

  const int nt = n >> 7;
  for (int t = 0; t < nt; t++) {
    const int cur = t & 1;
    if (t + 1 < nt) {
      const long kadv = (long)(t + 1) * 8192;   // 128 rows * 64 d
      const long vadv = (long)(t + 1) * 128;    // +128 j
#pragma unroll
      for (int p = 0; p < 4; p++) {
        gl_lds16(Kg + kadv + ksrc[p], &Ks[cur ^ 1][(tid + p * 256) * 8]);
        gl_lds16(Vg + vadv + vsrc[p], &Vs[cur ^ 1][(tid + p * 256) * 8]);
      }
    }

    // ---- software pipeline over 32-j sub-tiles ----
    f32x16 s_cur, s_nxt;
    {  // QK(jt=0)
      const int j = ql, sw = j & 7;
      __builtin_amdgcn_s_setprio(1);
      const f16x8 k0 = *(const f16x8*)(&Ks[cur][j * 64 + ((hi ^ sw) << 3)]);
      s_cur = MFMA32(k0, qf[0], initv);
#pragma unroll
      for (int kc = 1; kc < 4; kc++) {
        const f16x8 kf = *(const f16x8*)(&Ks[cur][j * 64 + ((((kc << 1) | hi) ^ sw) << 3)]);
        s_cur = MFMA32(kf, qf[kc], s_cur);
      }
      __builtin_amdgcn_s_setprio(0);
    }

#pragma unroll
    for (int jt = 0; jt < 4; jt++) {
      // issue QK(jt+1) — overlaps the softmax VALU below
      if (jt < 3) {
        const int j = (jt + 1) * 32 + ql, sw = j & 7;
        const f16x8 k0 = *(const f16x8*)(&Ks[cur][j * 64 + ((hi ^ sw) << 3)]);
        s_nxt = MFMA32(k0, qf[0], initv);
#pragma unroll
        for (int kc = 1; kc < 4; kc++) {
          const f16x8 kf = *(const f16x8*)(&Ks[cur][j * 64 + ((((kc << 1) | hi) ^ sw) << 3)]);
          s_nxt = MFMA32(kf, qf[kc], s_nxt);
        }
      }

      // softmax on s_cur: exp2 -> pack (rowsum handled by ones-MFMA below)
      int w[8];
#pragma unroll
      for (int m = 0; m < 8; m++) {
        const float pa = __builtin_amdgcn_exp2f(s_cur[2 * m]);
        const float pb = __builtin_amdgcn_exp2f(s_cur[2 * m + 1]);
        const auto h = __builtin_amdgcn_cvt_pkrtz(pa, pb);
        w[m] = __builtin_bit_cast(int, h);
      }
      // rebuild both kl P-fragments in registers
      f16x8 pf2[2];
#pragma unroll
      for (int kl = 0; kl < 2; kl++) {
        int a0 = w[4 * kl + 0], a1 = w[4 * kl + 1];
        int a2 = w[4 * kl + 2], a3 = w[4 * kl + 3];
        // v_permlane32_swap: dst.hi32lanes <-> src.lo32lanes
        asm volatile("v_permlane32_swap_b32 %0, %1" : "+v"(a0), "+v"(a2));
        asm volatile("v_permlane32_swap_b32 %0, %1" : "+v"(a1), "+v"(a3));
        i32x4 fi = {a0, a1, a2, a3};
        pf2[kl] = __builtin_bit_cast(f16x8, fi);
      }
      const f16x8 psum = pf2[0] + pf2[1];     // v_pk_add_f16; <= 2^15 < f16max

      // MFMA cluster: 1 ones-MFMA (rowsum) + 4 PV MFMAs
      __builtin_amdgcn_s_setprio(1);
      osum = MFMA32(psum, onesb, osum);
#pragma unroll
      for (int kl = 0; kl < 2; kl++) {
        const int kb = jt * 2 + kl;
#pragma unroll
        for (int dt = 0; dt < 2; dt++) {
          const int d = dt * 32 + ql;
          const f16x8 vf =
              *(const f16x8*)(&Vs[cur][d * 128 + ((((kb << 1) | hi) ^ (d & 15)) << 3)]);
          oacc[kl][dt] = MFMA32(pf2[kl], vf, oacc[kl][dt]);
        }
      }
      __builtin_amdgcn_s_setprio(0);
      if (jt < 3) s_cur = s_nxt;
    }

    __syncthreads();  // drains prefetch vmcnt + all waves done with buf[cur]
  }

  // osum[r] = full rowsum for q-row qloc(r) (duplicated across d-lanes);
  // no cross-lane reduction needed. Divide and store.
  const int bb = bh >> 3, hh = bh & 7;
#pragma unroll
  for (int r = 0; r < 16; r++) {
    const int qloc = (r & 3) + 8 * (r >> 2) + 4 * hi;
    const float inv = 1.f / fmaxf(osum[r], 0.016384f);  // 1e-6 * 2^14
    f16* dst = Ob + (((long)(bb * 4096 + q0w + qloc)) << 9) + hh * 64;
    dst[ql] = (f16)((oacc[0][0][r] + oacc[1][0][r]) * inv);
    dst[32 + ql] = (f16)((oacc[0][1][r] + oacc[1][1][r]) * inv);
  }
}

// ---------------------------------------------------------------------------
extern "C" void kernel_launch(void* const* d_in, const int* in_sizes, int n_in,
                              void* d_out, int out_size, void* d_ws, size_t ws_size,
                              hipStream_t stream) {
  const float* x   = (const float*)d_in[0];   // [2,4096,1024]
  const float* Wq  = (const float*)d_in[1];   // [1024,512]
  const float* Wkv = (const float*)d_in[2];   // [1024,1024]
  const float* Wo  = (const float*)d_in[3];   // [512,1024]
  float* out = (float*)d_out;                 // [2,4096,1024] fp32

  char* ws = (char*)d_ws;
  f16* Vt     = (f16*)(ws);                   //  8.39 MB  [16][64][4096]
  f16* Wqkv_t = (f16*)(ws + 16777216);        //  3.15 MB  [1536][1024]
  f16* Wo_t   = (f16*)(ws + 19922944);        //  1.05 MB  [1024][512]
  f16* Qb     = (f16*)(ws + 20971520);        //  8.39 MB  [16][4096][64]
  f16* Kb     = (f16*)(ws + 29360128);        //  8.39 MB
  f16* At     = (f16*)(ws + 46137344);        //  8.39 MB  [8192][512]

  // all weight transposes in one launch
  transpose_all_kernel<<<dim3(16, 16, 4), dim3(64, 8), 0, stream>>>(Wq, Wkv, Wo, Wqkv_t, Wo_t);

  // fused x-convert + QKV projection + l2norm (+Q prescale) + V-transpose:
  // [8192 x 1536 x 1024]
  gemm_kernel<1><<<768, 256, 0, stream>>>(nullptr, Wqkv_t, nullptr, Qb, Kb, Vt, x,
                                          8192, 1536, 1024);
  // attention (512 blocks, XCD-decoded inside)
  attn_kernel<<<512, 256, 0, stream>>>(Qb, Kb, Vt, At, 4096);
  // output projection: [8192 x 1024 x 512]
  gemm_kernel<0><<<512, 256, 0, stream>>>(At, Wo_t, out, nullptr, nullptr, nullptr, nullptr,
                                          8192, 1024, 512);
}